// Round 1
// baseline (217.115 us; speedup 1.0000x reference)
//
#include <hip/hip_runtime.h>
#include <math.h>

// Problem constants: x is [B=16, H=64, W=64, G*C=512], G=8, C=64.
#define BATCH   16
#define HW      4096          // H*W
#define CG      512           // G*C floats per position
#define NPAIR   36            // upper-triangular 8x8 pairs
#define F4_PER_POS   128      // 512 floats / 4
#define F4_PER_GROUP 16       // 64 floats / 4
#define SLOTS_PER_B  65536    // HW * 16 float4-slots per batch
#define XB_F4        524288   // HW * 128 float4 per batch

// ---------------------------------------------------------------------------
// Kernel 1: per-batch 8x8 Gram matrix S[b][g][g'] = sum_{h,w,c} x_g * x_g'
// Stored upper-triangular (36 entries) in d_ws, accumulated with atomicAdd.
// grid = (64, 16), block = 256.
// ---------------------------------------------------------------------------
__global__ __launch_bounds__(256) void gram_kernel(const float* __restrict__ xf,
                                                   float* __restrict__ S) {
    const float4* x = (const float4*)xf;
    const int b = blockIdx.y;
    const int stride = gridDim.x * 256;
    int t = blockIdx.x * 256 + threadIdx.x;

    float acc[NPAIR];
#pragma unroll
    for (int p = 0; p < NPAIR; ++p) acc[p] = 0.f;

    const float4* xb = x + (long)b * XB_F4;
    for (int slot = t; slot < SLOTS_PER_B; slot += stride) {
        const int pos = slot >> 4;
        const int c4  = slot & 15;
        const float4* ptr = xb + pos * F4_PER_POS + c4;
        float4 xg[8];
#pragma unroll
        for (int g = 0; g < 8; ++g) xg[g] = ptr[g * F4_PER_GROUP];
        int p = 0;
#pragma unroll
        for (int g = 0; g < 8; ++g) {
#pragma unroll
            for (int gp = g; gp < 8; ++gp, ++p) {
                acc[p] += xg[g].x * xg[gp].x + xg[g].y * xg[gp].y +
                          xg[g].z * xg[gp].z + xg[g].w * xg[gp].w;
            }
        }
    }

    // wave-level butterfly reduction (wave = 64 lanes on gfx950)
#pragma unroll
    for (int p = 0; p < NPAIR; ++p) {
        float v = acc[p];
#pragma unroll
        for (int off = 32; off; off >>= 1) v += __shfl_xor(v, off, 64);
        acc[p] = v;
    }

    __shared__ float red[4][NPAIR];
    const int lane = threadIdx.x & 63;
    const int wave = threadIdx.x >> 6;
    if (lane == 0) {
#pragma unroll
        for (int p = 0; p < NPAIR; ++p) red[wave][p] = acc[p];
    }
    __syncthreads();
    if (threadIdx.x < NPAIR) {
        float v = red[0][threadIdx.x] + red[1][threadIdx.x] +
                  red[2][threadIdx.x] + red[3][threadIdx.x];
        atomicAdd(&S[b * NPAIR + threadIdx.x], v);
    }
}

// ---------------------------------------------------------------------------
// Kernel 2: recompute alpha2 from S per block (trivial), then
// out[b,pos,c] = sum_g alpha2[b,g] * x[b,pos,g*64+c].
// grid = 4096 (256 blocks per batch), block = 256, one float4 out per thread.
// ---------------------------------------------------------------------------
__global__ __launch_bounds__(256) void out_kernel(const float* __restrict__ xf,
                                                  const float* __restrict__ S,
                                                  float* __restrict__ outf) {
    const float4* x = (const float4*)xf;
    float4* out = (float4*)outf;
    const int b   = blockIdx.x >> 8;    // 256 blocks per batch
    const int blk = blockIdx.x & 255;

    __shared__ float alpha1s[8];
    __shared__ float alpha2s[8];

    const int g = threadIdx.x;
    float row[8];
    float beta1 = 0.f;
    if (g < 8) {
#pragma unroll
        for (int gp = 0; gp < 8; ++gp) {
            const int a  = g < gp ? g : gp;
            const int bb = g < gp ? gp : g;
            const int idx = a * 8 - (a * (a - 1)) / 2 + (bb - a);
            row[gp] = S[b * NPAIR + idx];
            beta1 += row[gp];
        }
        beta1 *= 0.5f;
        alpha1s[g] = 1.f / (1.f + expf(-beta1));
    }
    __syncthreads();
    if (g < 8) {
        float beta2 = beta1;
#pragma unroll
        for (int gp = 0; gp < 8; ++gp) beta2 += alpha1s[gp] * row[gp];
        alpha2s[g] = 1.f / (1.f + expf(-beta2));
    }
    __syncthreads();

    float a[8];
#pragma unroll
    for (int gg = 0; gg < 8; ++gg) a[gg] = alpha2s[gg];

    const int t   = blk * 256 + threadIdx.x;   // [0, 65536) slot within batch
    const int pos = t >> 4;
    const int c4  = t & 15;
    const float4* ptr = x + (long)b * XB_F4 + pos * F4_PER_POS + c4;

    float4 accv = make_float4(0.f, 0.f, 0.f, 0.f);
#pragma unroll
    for (int gg = 0; gg < 8; ++gg) {
        const float4 v = ptr[gg * F4_PER_GROUP];
        accv.x += a[gg] * v.x;
        accv.y += a[gg] * v.y;
        accv.z += a[gg] * v.z;
        accv.w += a[gg] * v.w;
    }
    out[(long)b * SLOTS_PER_B + t] = accv;
}

extern "C" void kernel_launch(void* const* d_in, const int* in_sizes, int n_in,
                              void* d_out, int out_size, void* d_ws, size_t ws_size,
                              hipStream_t stream) {
    const float* x = (const float*)d_in[0];
    float* out = (float*)d_out;
    float* S = (float*)d_ws;   // 16 * 36 floats = 2304 bytes

    hipMemsetAsync(S, 0, BATCH * NPAIR * sizeof(float), stream);

    dim3 g1(64, BATCH);
    gram_kernel<<<g1, 256, 0, stream>>>(x, S);
    out_kernel<<<BATCH * 256, 256, 0, stream>>>(x, S, out);
}